// Round 10
// baseline (34.810 us; speedup 1.0000x reference)
//
#include <hip/hip_runtime.h>

#define HH 512
#define WW 512
#define NB 8
constexpr int   NPIX = HH * WW;              // 262144 pixels per batch
constexpr int   FH   = (HH - 1) * (WW - 1);  // 261121 lower faces per batch
constexpr int   NF   = 2 * FH;               // 522242 faces per batch
constexpr float EPS       = 0.04f;
constexpr float DEPTH_MIN = 0.1f;
constexpr float EDGE_MAX  = 0.1f;

__device__ __forceinline__ float elen(float ax, float ay, float az,
                                      float bx, float by, float bz) {
    float dx = ax - bx, dy = ay - by, dz = az - bz;
    return sqrtf(dx * dx + dy * dy + dz * dz);
}

// per-wave LDS -> global copy of n floats; d is 4B-aligned, head fixup to 16B.
// Single-wave workgroup: wave-ordered DS, no barrier needed.  (R4-proven)
__device__ __forceinline__ void wcopy(const float* __restrict__ s,
                                      float* __restrict__ d, int n, int lane) {
    int head = (int)(((16u - (unsigned)((uintptr_t)d & 15u)) & 15u) >> 2);
    if (head > n) head = n;
    if (lane < head) d[lane] = s[lane];
    int n4 = (n - head) >> 2;
    const float* s2 = s + head;
    float* d2 = d + head;            // 16B aligned
    for (int i = lane; i < n4; i += 64) {
        float4 t = make_float4(s2[4*i], s2[4*i+1], s2[4*i+2], s2[4*i+3]);
        *(float4*)(d2 + 4*i) = t;    // 1024B contiguous per instruction
    }
    int done = n4 << 2;
    int rem  = n - head - done;
    if (lane < rem) d2[done + lane] = s2[done + lane];
}

// One wave (= one 64-thread workgroup) = (batch b, face-row y).
// Lane owns interleaved columns lane + 64*j, j=0..7 (R4 ownership).
// Neighbors are RECOMPUTED from z(col+1) (L1-hot load) instead of shuffled:
// identical expressions -> bitwise-identical edge values, zero bpermutes.
__global__ void __launch_bounds__(64)
fused_kernel(const float* __restrict__ attr_d,
             const float* __restrict__ c2w_int,
             const float* __restrict__ c2w_ext,
             float* __restrict__ out_v,
             float* __restrict__ out_a,
             float* __restrict__ out_e,
             float* __restrict__ out_m) {
    __shared__ float ldsA[1536];
    __shared__ float ldsB[1536];
    const int lane = threadIdx.x;
    const int task = blockIdx.x;             // b*511 + y
    const int b    = task / 511;
    const int y    = task - b * 511;

    const float* base  = attr_d + (size_t)b * 4 * NPIX;  // planar (C,H,W)
    const float* zrow0 = base + 3 * NPIX + (size_t)y * WW;
    const float* zrow1 = zrow0 + WW;

    float z0[8], z1[8], a0[3][8];
#pragma unroll
    for (int j = 0; j < 8; ++j) {            // 4B-stride coalesced loads
        z0[j] = zrow0[lane + 64*j];
        z1[j] = zrow1[lane + 64*j];
    }
#pragma unroll
    for (int c = 0; c < 3; ++c) {
        const float* ar = base + c * NPIX + (size_t)y * WW;
#pragma unroll
        for (int j = 0; j < 8; ++j) a0[c][j] = ar[lane + 64*j];
    }

    // col-511 attribute extension (applies to rows 0..510; here y<=510)
#pragma unroll
    for (int c = 0; c < 3; ++c) {
        float left = __shfl_up(a0[c][7], 1);         // lane63 <- col510 value
        if (lane == 63) a0[c][7] += (a0[c][7] - left) * EPS;
    }

    const float* K = c2w_int + b * 9;
    const float* E = c2w_ext + b * 12;
    const float K0=K[0],K1=K[1],K2=K[2],K3=K[3],K4=K[4],K5=K[5],K6=K[6],K7=K[7],K8=K[8];
    const float E0=E[0],E1=E[1],E2=E[2],E3=E[3],E4=E[4],E5=E[5],
                E6=E[6],E7=E[7],E8=E[8],E9=E[9],E10=E[10],E11=E[11];

    const float yc0 = (float)y + 0.5f;
    const float yc1 = (y + 1 == HH - 1) ? ((float)HH - 0.5f + EPS)
                                        : ((float)(y + 1) + 0.5f);

    // unprojection helper (macro keeps identical expression order everywhere)
#define UNPROJ(xc, yc, zz, ox, oy, oz)                      \
    {   float p0 = (xc)*(zz), p1 = (yc)*(zz);               \
        float vi0 = K0*p0 + K1*p1 + K2*(zz);                \
        float vi1 = K3*p0 + K4*p1 + K5*(zz);                \
        float vi2 = K6*p0 + K7*p1 + K8*(zz);                \
        ox = E0*vi0 + E1*vi1 + E2 *vi2 + E3;                \
        oy = E4*vi0 + E5*vi1 + E6 *vi2 + E7;                \
        oz = E8*vi0 + E9*vi1 + E10*vi2 + E11; }

    float v0x[8],v0y[8],v0z[8], v1x[8],v1y[8],v1z[8];
#pragma unroll
    for (int j = 0; j < 8; ++j) {
        int col = lane + 64*j;
        float xc = (col == WW - 1) ? ((float)WW - 0.5f + EPS) : ((float)col + 0.5f);
        UNPROJ(xc, yc0, z0[j], v0x[j], v0y[j], v0z[j]);
        UNPROJ(xc, yc1, z1[j], v1x[j], v1y[j], v1z[j]);
    }

    // ---- v row y, a row y: stride-3 scalar ds_writes (2-way, free) -> wcopy
    size_t rb = ((size_t)b * NPIX + (size_t)y * WW) * 3;   // 16B aligned
#pragma unroll
    for (int j = 0; j < 8; ++j) {
        int c3 = (lane + 64*j) * 3;
        ldsA[c3] = v0x[j]; ldsA[c3+1] = v0y[j]; ldsA[c3+2] = v0z[j];
    }
    wcopy(ldsA, out_v + rb, 1536, lane);
#pragma unroll
    for (int j = 0; j < 8; ++j) {
        int c3 = (lane + 64*j) * 3;
        ldsB[c3] = a0[0][j]; ldsB[c3+1] = a0[1][j]; ldsB[c3+2] = a0[2][j];
    }
    wcopy(ldsB, out_a + rb, 1536, lane);

    // ---- neighbor z columns (col+1), coalesced L1-hot loads, no shuffles
    float znt[8], znb[8];
#pragma unroll
    for (int j = 0; j < 8; ++j) {
        int col = lane + 64*j;
        int cn  = col + (col < WW - 1 ? 1 : 0);      // clamp keeps in-bounds
        znt[j] = zrow0[cn];
        znb[j] = zrow1[cn];
    }

    // ---- edges + masks: one pass per j, neighbors recomputed arithmetically
    size_t mlo = (size_t)b * NF + (size_t)y * (WW-1);
    size_t mup = mlo + FH;
#pragma unroll
    for (int j = 0; j < 8; ++j) {
        int col = lane + 64*j;
        int cn  = col + 1;
        float xcn = (cn == WW - 1) ? ((float)WW - 0.5f + EPS) : ((float)cn + 0.5f);

        float n0x,n0y,n0z, n1x,n1y,n1z;
        UNPROJ(xcn, yc0, znt[j], n0x, n0y, n0z);     // v(row y,   col+1)
        UNPROJ(xcn, yc1, znb[j], n1x, n1y, n1z);     // v(row y+1, col+1)

        float vert  = elen(v0x[j],v0y[j],v0z[j], v1x[j],v1y[j],v1z[j]);
        float vertn = elen(n0x,n0y,n0z, n1x,n1y,n1z);   // == vert at col+1 (bitwise)
        float top   = elen(v0x[j],v0y[j],v0z[j], n0x,n0y,n0z);
        float bot   = elen(v1x[j],v1y[j],v1z[j], n1x,n1y,n1z);
        float diag  = elen(v0x[j],v0y[j],v0z[j], n1x,n1y,n1z);

        bool ml = (z0[j] > DEPTH_MIN) & (z1[j] > DEPTH_MIN) & (znb[j] > DEPTH_MIN) &
                  (vert < EDGE_MAX) & (bot < EDGE_MAX) & (diag < EDGE_MAX);
        bool mu = (z0[j] > DEPTH_MIN) & (znb[j] > DEPTH_MIN) & (znt[j] > DEPTH_MIN) &
                  (diag < EDGE_MAX) & (vertn < EDGE_MAX) & (top < EDGE_MAX);

        if (col < WW - 1) {
            out_m[mlo + col] = ml ? 1.0f : 0.0f;     // 4B-stride coalesced
            out_m[mup + col] = mu ? 1.0f : 0.0f;
            int c3 = col * 3;
            ldsA[c3] = vert; ldsA[c3+1] = bot;   ldsA[c3+2] = diag;
            ldsB[c3] = diag; ldsB[c3+1] = vertn; ldsB[c3+2] = top;
        }
    }
    size_t elo = mlo * 3;
    wcopy(ldsA, out_e + elo, 1533, lane);
    wcopy(ldsB, out_e + elo + (size_t)FH * 3, 1533, lane);

    // ---- wave y==510 also owns pixel row 511 (v + extended a)
    if (y == HH - 2) {
        float a1[3][8];
#pragma unroll
        for (int c = 0; c < 3; ++c) {
            const float* ar = base + c * NPIX + (size_t)(HH-1) * WW;
#pragma unroll
            for (int j = 0; j < 8; ++j) a1[c][j] = ar[lane + 64*j];
            float dl = __shfl_up(a0[c][7], 1);       // col510 row510 (original)
#pragma unroll
            for (int j = 0; j < 8; ++j) {            // last-row rule, cols 0..510
                int col = lane + 64*j;
                if (col < WW - 1) a1[c][j] += (a1[c][j] - a0[c][j]) * EPS;
            }
            if (lane == 63) a1[c][7] += (a1[c][7] - dl) * EPS;   // corner: diag
        }
        size_t rb1 = ((size_t)b * NPIX + (size_t)(HH-1) * WW) * 3;
#pragma unroll
        for (int j = 0; j < 8; ++j) {
            int c3 = (lane + 64*j) * 3;
            ldsA[c3] = v1x[j]; ldsA[c3+1] = v1y[j]; ldsA[c3+2] = v1z[j];
        }
        wcopy(ldsA, out_v + rb1, 1536, lane);
#pragma unroll
        for (int j = 0; j < 8; ++j) {
            int c3 = (lane + 64*j) * 3;
            ldsB[c3] = a1[0][j]; ldsB[c3+1] = a1[1][j]; ldsB[c3+2] = a1[2][j];
        }
        wcopy(ldsB, out_a + rb1, 1536, lane);
    }
#undef UNPROJ
}

extern "C" void kernel_launch(void* const* d_in, const int* in_sizes, int n_in,
                              void* d_out, int out_size, void* d_ws, size_t ws_size,
                              hipStream_t stream) {
    const float* attr_d  = (const float*)d_in[0];
    const float* c2w_int = (const float*)d_in[1];
    const float* c2w_ext = (const float*)d_in[2];

    float* out   = (float*)d_out;
    float* out_v = out;                                  // B*N*3
    float* out_a = out + (size_t)NB * NPIX * 3;          // B*N*3
    float* out_e = out + (size_t)2 * NB * NPIX * 3;      // B*F*3
    float* out_m = out_e + (size_t)NB * NF * 3;          // B*F

    int tasks = NB * (HH - 1);                           // 4088 wave-tasks
    fused_kernel<<<tasks, 64, 0, stream>>>(attr_d, c2w_int, c2w_ext,
                                           out_v, out_a, out_e, out_m);
}

// Round 11
// 28.414 us; speedup vs baseline: 1.2251x; 1.2251x over previous
//
#include <hip/hip_runtime.h>

#define HH 512
#define WW 512
#define NB 8
constexpr int   NPIX = HH * WW;              // 262144 pixels per batch
constexpr int   FH   = (HH - 1) * (WW - 1);  // 261121 lower faces per batch
constexpr int   NF   = 2 * FH;               // 522242 faces per batch
constexpr float EPS       = 0.04f;
constexpr float DEPTH_MIN = 0.1f;
constexpr float EDGE_MAX  = 0.1f;

__device__ __forceinline__ float elen(float ax, float ay, float az,
                                      float bx, float by, float bz) {
    float dx = ax - bx, dy = ay - by, dz = az - bz;
    return sqrtf(dx * dx + dy * dy + dz * dz);
}

// neighbor-column fetch: value of the (col+1) owner.
// col = lane + 64*j; col+1 owner is lane+1 (same j) except lane 63 -> lane 0, j+1.
__device__ __forceinline__ float nbr(float cur, float nxt, int lane) {
    float t = (lane == 0) ? nxt : cur;
    return __shfl(t, (lane + 1) & 63);
}

// per-wave LDS -> global copy of n floats; d is 4B-aligned, head fixup to 16B.
// Single-wave workgroup: wave-ordered DS, no barrier needed.
__device__ __forceinline__ void wcopy(const float* __restrict__ s,
                                      float* __restrict__ d, int n, int lane) {
    int head = (int)(((16u - (unsigned)((uintptr_t)d & 15u)) & 15u) >> 2);
    if (head > n) head = n;
    if (lane < head) d[lane] = s[lane];
    int n4 = (n - head) >> 2;
    const float* s2 = s + head;
    float* d2 = d + head;            // 16B aligned
    for (int i = lane; i < n4; i += 64) {
        float4 t = make_float4(s2[4*i], s2[4*i+1], s2[4*i+2], s2[4*i+3]);
        *(float4*)(d2 + 4*i) = t;    // 1024B contiguous per instruction
    }
    int done = n4 << 2;
    int rem  = n - head - done;
    if (lane < rem) d2[done + lane] = s2[done + lane];
}

// One wave (= one 64-thread workgroup) handles (batch b, face-row y).
// Lane owns interleaved columns lane + 64*j, j=0..7.
__global__ void __launch_bounds__(64)
fused_kernel(const float* __restrict__ attr_d,
             const float* __restrict__ c2w_int,
             const float* __restrict__ c2w_ext,
             float* __restrict__ out_v,
             float* __restrict__ out_a,
             float* __restrict__ out_e,
             float* __restrict__ out_m) {
    __shared__ float lds[1536];
    const int lane = threadIdx.x;
    const int task = blockIdx.x;             // b*511 + y
    const int b    = task / 511;
    const int y    = task - b * 511;

    const float* base  = attr_d + (size_t)b * 4 * NPIX;  // planar (C,H,W)
    const float* zrow0 = base + 3 * NPIX + (size_t)y * WW;
    const float* zrow1 = zrow0 + WW;

    float z0[8], z1[8], a0[3][8];
#pragma unroll
    for (int j = 0; j < 8; ++j) {            // 4B-stride coalesced loads
        z0[j] = zrow0[lane + 64*j];
        z1[j] = zrow1[lane + 64*j];
    }
#pragma unroll
    for (int c = 0; c < 3; ++c) {
        const float* ar = base + c * NPIX + (size_t)y * WW;
#pragma unroll
        for (int j = 0; j < 8; ++j) a0[c][j] = ar[lane + 64*j];
    }

    // col-511 attribute extension (applies to rows 0..510; here y<=510)
#pragma unroll
    for (int c = 0; c < 3; ++c) {
        float left = __shfl_up(a0[c][7], 1);         // lane63 <- col510 value
        if (lane == 63) a0[c][7] += (a0[c][7] - left) * EPS;
    }

    const float* K = c2w_int + b * 9;
    const float* E = c2w_ext + b * 12;
    const float K0=K[0],K1=K[1],K2=K[2],K3=K[3],K4=K[4],K5=K[5],K6=K[6],K7=K[7],K8=K[8];
    const float E0=E[0],E1=E[1],E2=E[2],E3=E[3],E4=E[4],E5=E[5],
                E6=E[6],E7=E[7],E8=E[8],E9=E[9],E10=E[10],E11=E[11];

    const float yc0 = (float)y + 0.5f;
    const float yc1 = (y + 1 == HH - 1) ? ((float)HH - 0.5f + EPS)
                                        : ((float)(y + 1) + 0.5f);

    float v0x[8],v0y[8],v0z[8], v1x[8],v1y[8],v1z[8];
#pragma unroll
    for (int j = 0; j < 8; ++j) {
        int col = lane + 64*j;
        float xc = (col == WW - 1) ? ((float)WW - 0.5f + EPS) : ((float)col + 0.5f);
        {
            float p0 = xc*z0[j], p1 = yc0*z0[j], p2 = z0[j];
            float vi0 = K0*p0 + K1*p1 + K2*p2;
            float vi1 = K3*p0 + K4*p1 + K5*p2;
            float vi2 = K6*p0 + K7*p1 + K8*p2;
            v0x[j] = E0*vi0 + E1*vi1 + E2 *vi2 + E3;
            v0y[j] = E4*vi0 + E5*vi1 + E6 *vi2 + E7;
            v0z[j] = E8*vi0 + E9*vi1 + E10*vi2 + E11;
        }
        {
            float p0 = xc*z1[j], p1 = yc1*z1[j], p2 = z1[j];
            float vi0 = K0*p0 + K1*p1 + K2*p2;
            float vi1 = K3*p0 + K4*p1 + K5*p2;
            float vi2 = K6*p0 + K7*p1 + K8*p2;
            v1x[j] = E0*vi0 + E1*vi1 + E2 *vi2 + E3;
            v1y[j] = E4*vi0 + E5*vi1 + E6 *vi2 + E7;
            v1z[j] = E8*vi0 + E9*vi1 + E10*vi2 + E11;
        }
    }

    // ---- v row y, a row y: stride-3 scalar ds_writes (2-way, free) -> wcopy
    size_t rb = ((size_t)b * NPIX + (size_t)y * WW) * 3;   // 16B aligned
#pragma unroll
    for (int j = 0; j < 8; ++j) {
        int c3 = (lane + 64*j) * 3;
        lds[c3] = v0x[j]; lds[c3+1] = v0y[j]; lds[c3+2] = v0z[j];
    }
    wcopy(lds, out_v + rb, 1536, lane);
#pragma unroll
    for (int j = 0; j < 8; ++j) {
        int c3 = (lane + 64*j) * 3;
        lds[c3] = a0[0][j]; lds[c3+1] = a0[1][j]; lds[c3+2] = a0[2][j];
    }
    wcopy(lds, out_a + rb, 1536, lane);

    // ---- edges + masks
    float vert[8];
#pragma unroll
    for (int j = 0; j < 8; ++j)
        vert[j] = elen(v0x[j],v0y[j],v0z[j], v1x[j],v1y[j],v1z[j]);

    float bot[8], diag[8], top[8], vertn[8];
    size_t mlo = (size_t)b * NF + (size_t)y * (WW-1);
    size_t mup = mlo + FH;
#pragma unroll
    for (int j = 0; j < 8; ++j) {
        const int jn = (j < 7) ? j + 1 : j;   // j==7 nxt only feeds unused lane63
        float n0x = nbr(v0x[j], v0x[jn], lane);
        float n0y = nbr(v0y[j], v0y[jn], lane);
        float n0z = nbr(v0z[j], v0z[jn], lane);
        float n1x = nbr(v1x[j], v1x[jn], lane);
        float n1y = nbr(v1y[j], v1y[jn], lane);
        float n1z = nbr(v1z[j], v1z[jn], lane);
        float zt1 = nbr(z0[j],  z0[jn],  lane);
        float zb1 = nbr(z1[j],  z1[jn],  lane);
        vertn[j]  = nbr(vert[j], vert[jn], lane);

        top[j]  = elen(v0x[j],v0y[j],v0z[j], n0x,n0y,n0z);
        bot[j]  = elen(v1x[j],v1y[j],v1z[j], n1x,n1y,n1z);
        diag[j] = elen(v0x[j],v0y[j],v0z[j], n1x,n1y,n1z);

        bool ml = (z0[j] > DEPTH_MIN) & (z1[j] > DEPTH_MIN) & (zb1 > DEPTH_MIN) &
                  (vert[j] < EDGE_MAX) & (bot[j] < EDGE_MAX) & (diag[j] < EDGE_MAX);
        bool mu = (z0[j] > DEPTH_MIN) & (zb1 > DEPTH_MIN) & (zt1 > DEPTH_MIN) &
                  (diag[j] < EDGE_MAX) & (vertn[j] < EDGE_MAX) & (top[j] < EDGE_MAX);

        int col = lane + 64*j;
        if (col < WW - 1) {                   // 4B-stride coalesced mask stores
            out_m[mlo + col] = ml ? 1.0f : 0.0f;
            out_m[mup + col] = mu ? 1.0f : 0.0f;
        }
    }

    size_t elo = mlo * 3;
#pragma unroll
    for (int j = 0; j < 8; ++j) {
        int col = lane + 64*j;
        if (col < WW - 1) {
            int c3 = col * 3;
            lds[c3] = vert[j]; lds[c3+1] = bot[j]; lds[c3+2] = diag[j];
        }
    }
    wcopy(lds, out_e + elo, 1533, lane);
#pragma unroll
    for (int j = 0; j < 8; ++j) {
        int col = lane + 64*j;
        if (col < WW - 1) {
            int c3 = col * 3;
            lds[c3] = diag[j]; lds[c3+1] = vertn[j]; lds[c3+2] = top[j];
        }
    }
    wcopy(lds, out_e + elo + (size_t)FH * 3, 1533, lane);

    // ---- wave y==510 also owns pixel row 511 (v + extended a)
    if (y == HH - 2) {
        float a1[3][8];
#pragma unroll
        for (int c = 0; c < 3; ++c) {
            const float* ar = base + c * NPIX + (size_t)(HH-1) * WW;
#pragma unroll
            for (int j = 0; j < 8; ++j) a1[c][j] = ar[lane + 64*j];
            float dl = __shfl_up(a0[c][7], 1);       // col510 row510 (original)
#pragma unroll
            for (int j = 0; j < 8; ++j) {            // last-row rule, cols 0..510
                int col = lane + 64*j;
                if (col < WW - 1) a1[c][j] += (a1[c][j] - a0[c][j]) * EPS;
            }
            if (lane == 63) a1[c][7] += (a1[c][7] - dl) * EPS;   // corner: diag
        }
        size_t rb1 = ((size_t)b * NPIX + (size_t)(HH-1) * WW) * 3;
#pragma unroll
        for (int j = 0; j < 8; ++j) {
            int c3 = (lane + 64*j) * 3;
            lds[c3] = v1x[j]; lds[c3+1] = v1y[j]; lds[c3+2] = v1z[j];
        }
        wcopy(lds, out_v + rb1, 1536, lane);
#pragma unroll
        for (int j = 0; j < 8; ++j) {
            int c3 = (lane + 64*j) * 3;
            lds[c3] = a1[0][j]; lds[c3+1] = a1[1][j]; lds[c3+2] = a1[2][j];
        }
        wcopy(lds, out_a + rb1, 1536, lane);
    }
}

extern "C" void kernel_launch(void* const* d_in, const int* in_sizes, int n_in,
                              void* d_out, int out_size, void* d_ws, size_t ws_size,
                              hipStream_t stream) {
    const float* attr_d  = (const float*)d_in[0];
    const float* c2w_int = (const float*)d_in[1];
    const float* c2w_ext = (const float*)d_in[2];

    float* out   = (float*)d_out;
    float* out_v = out;                                  // B*N*3
    float* out_a = out + (size_t)NB * NPIX * 3;          // B*N*3
    float* out_e = out + (size_t)2 * NB * NPIX * 3;      // B*F*3
    float* out_m = out_e + (size_t)NB * NF * 3;          // B*F

    int tasks = NB * (HH - 1);                           // 4088 wave-tasks
    fused_kernel<<<tasks, 64, 0, stream>>>(attr_d, c2w_int, c2w_ext,
                                           out_v, out_a, out_e, out_m);
}